// Round 6
// baseline (479.359 us; speedup 1.0000x reference)
//
#include <hip/hip_runtime.h>
#include <hip/hip_bf16.h>

// MFW encdec multihead attention, MI355X — all-fp16 pipeline, v3 attn.
// build W -> cvt key -> KV GEMM (k16,v16) -> V transpose (vT) -> Q GEMM ->
// attn (256thr/32q/2 blocks-per-CU, streamed K and V^T chunks, probs after PV)
// -> out GEMM.  d_out FLOAT32: [out 8.4M | probs 134.2M].

typedef float  fx4 __attribute__((ext_vector_type(4)));
typedef short  sx8 __attribute__((ext_vector_type(8)));
typedef _Float16 hx8 __attribute__((ext_vector_type(8)));

__device__ __forceinline__ unsigned short f2h(float f) {
  return __builtin_bit_cast(unsigned short, (_Float16)f);
}
__device__ __forceinline__ float h2f(unsigned short h) {
  return (float)__builtin_bit_cast(_Float16, h);
}

__device__ __forceinline__ void gload_lds16(const void* g, void* l) {
  __builtin_amdgcn_global_load_lds((const __attribute__((address_space(1))) void*)g,
                                   (__attribute__((address_space(3))) void*)l, 16, 0, 0);
}

__device__ __forceinline__ fx4 mfma_h(sx8 a, sx8 b, fx4 c) {
  return __builtin_amdgcn_mfma_f32_16x16x32_f16(__builtin_bit_cast(hx8, a),
                                                __builtin_bit_cast(hx8, b), c, 0, 0, 0);
}

// barrier after gload_lds staging: drain vmem (untracked gloads), sync.
__device__ __forceinline__ void wait_vm_bar() {
  __builtin_amdgcn_sched_barrier(0);
  asm volatile("s_waitcnt vmcnt(0)" ::: "memory");
  __builtin_amdgcn_s_barrier();
  __builtin_amdgcn_sched_barrier(0);
}
// LDS-only barrier (stores stay in flight)
__device__ __forceinline__ void bar_lgkm() {
  __builtin_amdgcn_sched_barrier(0);
  asm volatile("s_waitcnt lgkmcnt(0)" ::: "memory");
  __builtin_amdgcn_s_barrier();
  __builtin_amdgcn_sched_barrier(0);
}

// ---------------------------------------------------------------------------
// Kernel 1: build adapted weights (fp16).
// ---------------------------------------------------------------------------
__global__ void k_build_w(
    const float* wq, const float* wkv, const float* wo,
    const float* r_q, const float* s_q, const float* r_kv, const float* s_kv,
    const float* r_o, const float* s_o,
    const float* rm_q, const float* sm_q, const float* rm_kv, const float* sm_kv,
    const float* rm_o, const float* sm_o,
    const int* src_i, const int* tgt_i,
    unsigned short* Wq16, unsigned short* Wkv16, unsigned short* Wo16)
{
  const int it = tgt_i[0], is = src_i[0];
  const int gid = blockIdx.x * 256 + threadIdx.x;
  const int mat = gid >> 20;
  const int idx = gid & 1048575;
  const int o = idx >> 10, i = idx & 1023;
  float lrm = 0.f, lr = 0.f;
  if (mat == 0) {
    #pragma unroll
    for (int r = 0; r < 4; ++r) {
      lrm += rm_q[(it * 4 + r) * 1024 + o] * sm_q[(is * 4 + r) * 1024 + i];
      lr  += r_q [(it * 4 + r) * 1024 + o] * s_q [(is * 4 + r) * 1024 + i];
    }
    Wq16[idx] = f2h((wq[idx] * lrm + lr) * 0.125f);
  } else if (mat == 1) {
    #pragma unroll
    for (int r = 0; r < 4; ++r) {
      lrm += rm_kv[(it * 4 + r) * 2048 + o] * sm_kv[(is * 4 + r) * 1024 + i];
      lr  += r_kv [(it * 4 + r) * 2048 + o] * s_kv [(is * 4 + r) * 1024 + i];
    }
    Wkv16[idx] = f2h(wkv[idx] * lrm + lr);
  } else if (mat == 2) {
    #pragma unroll
    for (int r = 0; r < 4; ++r) {
      lrm += rm_kv[(it * 4 + r) * 2048 + 1024 + o] * sm_kv[(is * 4 + r) * 1024 + i];
      lr  += r_kv [(it * 4 + r) * 2048 + 1024 + o] * s_kv [(is * 4 + r) * 1024 + i];
    }
    Wkv16[1048576 + idx] = f2h(wkv[1048576 + idx] * lrm + lr);
  } else {
    #pragma unroll
    for (int r = 0; r < 4; ++r) {
      lrm += rm_o[(it * 4 + r) * 1024 + o] * sm_o[(is * 4 + r) * 1024 + i];
      lr  += r_o [(it * 4 + r) * 1024 + o] * s_o [(is * 4 + r) * 1024 + i];
    }
    Wo16[idx] = f2h(wo[idx] * lrm + lr);
  }
}

// ---------------------------------------------------------------------------
// Kernel 1b: convert key f32 -> fp16.
// ---------------------------------------------------------------------------
__global__ void k_cvt(const float* k, unsigned short* kh)
{
  const int gid = blockIdx.x * 256 + threadIdx.x;   // 0 .. 1M-1
  const size_t off = (size_t)gid * 8;
  fx4 a = *(const fx4*)(k + off), bv = *(const fx4*)(k + off + 4);
  sx8 h;
  #pragma unroll
  for (int j = 0; j < 4; ++j) { h[j] = (short)f2h(a[j]); h[4 + j] = (short)f2h(bv[j]); }
  *(sx8*)(kh + off) = h;
}

// ---------------------------------------------------------------------------
// Kernel 2: C = A * B^T, 128x128 tile, BK=32, 4 waves (m97 structure).
// AMODE 0: A f32 -> fp16 VALU-staged.  AMODE 1: A fp16 via global_load_lds.
// OUT 0: fp16 C[row*1024+col]   OUT 1: split k16/v16   OUT 2: f32 Cf.
// ---------------------------------------------------------------------------
template<int AMODE, int OUT>
__global__ __launch_bounds__(256, 2) void k_gemm(
    const float* Af, const unsigned short* Ah, const unsigned short* B,
    unsigned short* C0, unsigned short* C1, float* Cf)
{
  __shared__ unsigned short lds[2][2][4096];
  const int tid = threadIdx.x;
  const int l = tid & 63, wid = tid >> 6;
  const int wr = wid >> 1, wc = wid & 1;
  const int mBase = blockIdx.y * 128, nBase = blockIdx.x * 128;
  const int brow = tid >> 2, bc8 = (tid & 3) * 8;
  const int arow = tid >> 1, ac16 = (tid & 1) * 16;

  fx4 acc[4][4] = {};

  auto stage = [&](int buf, int kt) {
    const int kB = kt * 32;
    gload_lds16(B + (size_t)(nBase + brow) * 1024 + kB + bc8,      &lds[buf][1][tid * 8]);
    gload_lds16(B + (size_t)(nBase + 64 + brow) * 1024 + kB + bc8, &lds[buf][1][2048 + tid * 8]);
    if constexpr (AMODE == 1) {
      gload_lds16(Ah + (size_t)(mBase + brow) * 1024 + kB + bc8,      &lds[buf][0][tid * 8]);
      gload_lds16(Ah + (size_t)(mBase + 64 + brow) * 1024 + kB + bc8, &lds[buf][0][2048 + tid * 8]);
    } else {
      const float* asrc = Af + (size_t)(mBase + arow) * 1024 + kB + ac16;
      sx8 h0, h1;
      #pragma unroll
      for (int p = 0; p < 4; ++p) {
        fx4 vv = *(const fx4*)(asrc + p * 4);
        #pragma unroll
        for (int j = 0; j < 4; ++j) {
          const unsigned short hv = f2h(vv[j]);
          const int pos = p * 4 + j;
          if (pos < 8) h0[pos] = (short)hv; else h1[pos - 8] = (short)hv;
        }
      }
      *(sx8*)&lds[buf][0][arow * 32 + ac16]     = h0;
      *(sx8*)&lds[buf][0][arow * 32 + ac16 + 8] = h1;
    }
  };

  auto compute = [&](int buf) {
    sx8 af[4], bfv[4];
    #pragma unroll
    for (int x = 0; x < 4; ++x) {
      af[x]  = *(const sx8*)&lds[buf][0][(wr * 64 + x * 16 + (l & 15)) * 32 + (l >> 4) * 8];
      bfv[x] = *(const sx8*)&lds[buf][1][(wc * 64 + x * 16 + (l & 15)) * 32 + (l >> 4) * 8];
    }
    #pragma unroll
    for (int mi = 0; mi < 4; ++mi)
      #pragma unroll
      for (int ni = 0; ni < 4; ++ni)
        acc[mi][ni] = mfma_h(af[mi], bfv[ni], acc[mi][ni]);
  };

  stage(0, 0);
  __syncthreads();
  for (int kt = 0; kt < 32; ++kt) {
    const int buf = kt & 1;
    if (kt + 1 < 32) stage(buf ^ 1, kt + 1);
    compute(buf);
    __syncthreads();
  }

  #pragma unroll
  for (int mi = 0; mi < 4; ++mi)
    #pragma unroll
    for (int ni = 0; ni < 4; ++ni)
      #pragma unroll
      for (int i = 0; i < 4; ++i) {
        const size_t row = (size_t)(mBase + wr * 64 + mi * 16 + (l >> 4) * 4 + i);
        const int col = nBase + wc * 64 + ni * 16 + (l & 15);
        const float x = acc[mi][ni][i];
        if constexpr (OUT == 0)      C0[row * 1024 + col] = f2h(x);
        else if constexpr (OUT == 2) Cf[row * 1024 + col] = x;
        else {
          if (nBase < 1024) C0[row * 1024 + col] = f2h(x);
          else              C1[row * 1024 + (col - 1024)] = f2h(x);
        }
      }
}

// ---------------------------------------------------------------------------
// Kernel 2b: per-head V transpose: v16 [(k*8+b)*1024 + h*64 + d] ->
// vT [((b*16+h)*64 + d)*1024 + k].  64x64 tiles via LDS.
// ---------------------------------------------------------------------------
__global__ __launch_bounds__(256) void k_vt(const unsigned short* v16, unsigned short* vT)
{
  __shared__ unsigned short t[64 * 72];
  const int tid = threadIdx.x;
  const int head = blockIdx.x >> 4, kb = blockIdx.x & 15;
  const int b = head >> 4, hh = head & 15;
  const int kl = tid >> 2, part = tid & 3;
  #pragma unroll
  for (int u = 0; u < 2; ++u) {
    sx8 v = *(const sx8*)&v16[(size_t)((kb * 64 + kl) * 8 + b) * 1024 + hh * 64 + part * 16 + u * 8];
    *(sx8*)&t[kl * 72 + part * 16 + u * 8] = v;
  }
  __syncthreads();
  const int dr = tid >> 2;
  unsigned short out[16];
  #pragma unroll
  for (int j = 0; j < 16; ++j) out[j] = t[(part * 16 + j) * 72 + dr];
  unsigned short* dst = vT + (size_t)((b * 16 + hh) * 64 + dr) * 1024 + kb * 64 + part * 16;
  *(sx8*)dst       = *(sx8*)&out[0];
  *(sx8*)(dst + 8) = *(sx8*)&out[8];
}

// ---------------------------------------------------------------------------
// Kernel 3: FUSED attn v3.  Block = 256 thr / 4 waves / 32 q-rows.
// LDS exactly 80 KB (Pl 64 KB + Sb 16 KB, reduce arrays aliased in Sb)
// -> 2 blocks/CU.  Waves: QK^T (qg, half) 16q x 512k; PV (qg, dh) 16q x 32d.
// K streamed 16 x 8KB chunks (dbuf, stage/waitvm+bar/compute); softmax exact;
// P fp16 -> Pl; PV streams V^T chunks identically; probs f32 written AFTER PV.
// ---------------------------------------------------------------------------
__global__ __launch_bounds__(256, 2) void k_attn(
    const unsigned short* q16, const unsigned short* k16, const unsigned short* vT,
    float* probsF, unsigned short* ctx)
{
  __shared__ __align__(16) unsigned short Pl[32 * 1024];   // 64 KB: P (fp16, swizzled)
  __shared__ __align__(16) unsigned short Sb[2][4096];     // 16 KB: K / V^T chunk dbuf
  float* redm = (float*)&Sb[0][0];    // [32 rows][2 half] — aliased, used post-QK^T
  float* reds = redm + 64;

  const int tid = threadIdx.x, l = tid & 63, wid = tid >> 6;
  const int qg = wid >> 1, half = wid & 1;   // PV reuses half as dh
  const int bid = blockIdx.x;
  const int logical = (bid & 7) * 512 + (bid >> 3);  // XCD-grouped, bijective
  const int head = logical >> 5, qb = logical & 31;
  const int b = head >> 4, hh = head & 15;

  // Q fragments (16 q-rows per wave, fp16)
  sx8 qf[2];
  {
    const int qrow = qb * 32 + qg * 16 + (l & 15);
    const size_t qoff = (size_t)(qrow * 8 + b) * 1024 + hh * 64 + (l >> 4) * 8;
    qf[0] = *(const sx8*)&q16[qoff];
    qf[1] = *(const sx8*)&q16[qoff + 32];
  }

  // ---- QK^T: stream K in 16 chunks of 64 rows (32 per half) ---------------
  auto stage_k = [&](int buf, int c) {
    #pragma unroll
    for (int g = 0; g < 2; ++g) {
      const int e = g * 256 + tid;
      const int rl = e >> 3, ch = e & 7;
      const int krow = (rl < 32) ? (c * 32 + rl) : (512 + c * 32 + (rl - 32));
      gload_lds16(k16 + (size_t)(krow * 8 + b) * 1024 + hh * 64 + ((ch ^ (rl & 7)) * 8),
                  &Sb[buf][e * 8]);
    }
  };

  fx4 acc[32];
  #pragma unroll
  for (int s = 0; s < 32; ++s) acc[s] = fx4{0.f, 0.f, 0.f, 0.f};

  stage_k(0, 0);
  #pragma unroll
  for (int c = 0; c < 16; ++c) {
    const int buf = c & 1;
    wait_vm_bar();
    if (c + 1 < 16) stage_k(buf ^ 1, c + 1);
    #pragma unroll
    for (int nt = 0; nt < 2; ++nt) {
      const int rl = half * 32 + nt * 16 + (l & 15);
      sx8 kb0 = *(const sx8*)&Sb[buf][rl * 64 + (((l >> 4)) ^ (rl & 7)) * 8];
      sx8 kb1 = *(const sx8*)&Sb[buf][rl * 64 + ((4 + (l >> 4)) ^ (rl & 7)) * 8];
      acc[c * 2 + nt] = mfma_h(qf[0], kb0, acc[c * 2 + nt]);
      acc[c * 2 + nt] = mfma_h(qf[1], kb1, acc[c * 2 + nt]);
    }
  }

  // ---- softmax (rows r = qg*16 + (l>>4)*4 + i, cols half*512 + s*16 + (l&15))
  const int rg = l >> 4;
  float mloc[4] = {-3e38f, -3e38f, -3e38f, -3e38f};
  #pragma unroll
  for (int s = 0; s < 32; ++s)
    #pragma unroll
    for (int i = 0; i < 4; ++i) mloc[i] = fmaxf(mloc[i], acc[s][i]);
  #pragma unroll
  for (int msk = 1; msk <= 8; msk <<= 1)
    #pragma unroll
    for (int i = 0; i < 4; ++i) mloc[i] = fmaxf(mloc[i], __shfl_xor(mloc[i], msk));
  if ((l & 15) == 0) {
    #pragma unroll
    for (int i = 0; i < 4; ++i) redm[(qg * 16 + rg * 4 + i) * 2 + half] = mloc[i];
  }
  bar_lgkm();
  float mfull[4], sloc[4] = {0.f, 0.f, 0.f, 0.f};
  #pragma unroll
  for (int i = 0; i < 4; ++i) {
    const int r = qg * 16 + rg * 4 + i;
    mfull[i] = fmaxf(redm[r * 2], redm[r * 2 + 1]);
  }
  #pragma unroll
  for (int s = 0; s < 32; ++s)
    #pragma unroll
    for (int i = 0; i < 4; ++i) {
      const float e = __expf(acc[s][i] - mfull[i]);
      acc[s][i] = e;
      sloc[i] += e;
    }
  #pragma unroll
  for (int msk = 1; msk <= 8; msk <<= 1)
    #pragma unroll
    for (int i = 0; i < 4; ++i) sloc[i] += __shfl_xor(sloc[i], msk);
  if ((l & 15) == 0) {
    #pragma unroll
    for (int i = 0; i < 4; ++i) reds[(qg * 16 + rg * 4 + i) * 2 + half] = sloc[i];
  }
  bar_lgkm();
  float inv[4];
  #pragma unroll
  for (int i = 0; i < 4; ++i) {
    const int r = qg * 16 + rg * 4 + i;
    inv[i] = 1.0f / (reds[r * 2] + reds[r * 2 + 1]);
  }

  // ---- P (fp16, 16B-chunk XOR swizzle) -> Pl -------------------------------
  #pragma unroll
  for (int s = 0; s < 32; ++s)
    #pragma unroll
    for (int i = 0; i < 4; ++i) {
      const int row = qg * 16 + rg * 4 + i;
      const int col = half * 512 + s * 16 + (l & 15);
      Pl[row * 1024 + ((col >> 3) ^ (row & 7)) * 8 + (col & 7)] = f2h(acc[s][i] * inv[i]);
    }
  bar_lgkm();

  // ---- PV: stream V^T in 16 chunks of 64 k-cols ----------------------------
  auto stage_v = [&](int buf, int c) {
    #pragma unroll
    for (int g = 0; g < 2; ++g) {
      const int e = g * 256 + tid;
      const int dr = e >> 3, ch = e & 7;
      gload_lds16(vT + (size_t)((b * 16 + hh) * 64 + dr) * 1024 + c * 64 + ((ch ^ (dr & 7)) * 8),
                  &Sb[buf][e * 8]);
    }
  };

  const int dh = half;
  fx4 cacc[2] = {};
  stage_v(0, 0);
  #pragma unroll
  for (int c = 0; c < 16; ++c) {
    const int buf = c & 1;
    wait_vm_bar();
    if (c + 1 < 16) stage_v(buf ^ 1, c + 1);
    #pragma unroll
    for (int kk = 0; kk < 2; ++kk) {
      const int prow = qg * 16 + (l & 15);
      const int pc16 = (c * 8 + kk * 4 + (l >> 4)) ^ (prow & 7);
      sx8 pa = *(const sx8*)&Pl[prow * 1024 + pc16 * 8];
      #pragma unroll
      for (int ni = 0; ni < 2; ++ni) {
        const int dr = dh * 32 + ni * 16 + (l & 15);
        sx8 vb = *(const sx8*)&Sb[buf][dr * 64 + ((kk * 4 + (l >> 4)) ^ (dr & 7)) * 8];
        cacc[ni] = mfma_h(pa, vb, cacc[ni]);
      }
    }
  }

  // ctx out (fp16, (lq,b,E) layout)
  #pragma unroll
  for (int ni = 0; ni < 2; ++ni)
    #pragma unroll
    for (int i = 0; i < 4; ++i) {
      const int q = qb * 32 + qg * 16 + (l >> 4) * 4 + i;
      const int d = dh * 32 + ni * 16 + (l & 15);
      ctx[(size_t)(q * 8 + b) * 1024 + hh * 64 + d] = f2h(cacc[ni][i]);
    }

  // ---- probs f32, coalesced from Pl (Pl untouched by PV) -------------------
  {
    const size_t pbase = (size_t)head * 1048576;
    #pragma unroll
    for (int i = 0; i < 32; ++i) {
      const int row = wid * 8 + (i >> 2);
      const int col = (i & 3) * 256 + l * 4;
      const int c16 = ((col >> 3) ^ (row & 7));
      const unsigned* raw = (const unsigned*)&Pl[row * 1024 + c16 * 8 + (col & 7)];
      const unsigned r0 = raw[0], r1 = raw[1];
      fx4 o;
      o[0] = h2f((unsigned short)(r0 & 0xffffu)); o[1] = h2f((unsigned short)(r0 >> 16));
      o[2] = h2f((unsigned short)(r1 & 0xffffu)); o[3] = h2f((unsigned short)(r1 >> 16));
      *(fx4*)&probsF[pbase + (size_t)(qb * 32 + row) * 1024 + col] = o;
    }
  }
}

// ---------------------------------------------------------------------------
extern "C" void kernel_launch(void* const* d_in, const int* in_sizes, int n_in,
                              void* d_out, int out_size, void* d_ws, size_t ws_size,
                              hipStream_t stream)
{
  const float* query = (const float*)d_in[0];
  const float* key   = (const float*)d_in[1];
  const float* wq    = (const float*)d_in[2];
  const float* wkv   = (const float*)d_in[3];
  const float* wo    = (const float*)d_in[4];
  const float* r_q   = (const float*)d_in[5];
  const float* s_q   = (const float*)d_in[6];
  const float* r_kv  = (const float*)d_in[7];
  const float* s_kv  = (const float*)d_in[8];
  const float* r_o   = (const float*)d_in[9];
  const float* s_o   = (const float*)d_in[10];
  const float* rm_q  = (const float*)d_in[11];
  const float* sm_q  = (const float*)d_in[12];
  const float* rm_kv = (const float*)d_in[13];
  const float* sm_kv = (const float*)d_in[14];
  const float* rm_o  = (const float*)d_in[15];
  const float* sm_o  = (const float*)d_in[16];
  const int* src_i   = (const int*)d_in[17];
  const int* tgt_i   = (const int*)d_in[18];

  unsigned short* ws16 = (unsigned short*)d_ws;
  const size_t M1 = 1048576, M8 = 8388608;
  unsigned short* Wq16  = ws16;                // 1M
  unsigned short* Wkv16 = ws16 + M1;           // 2M
  unsigned short* Wo16  = ws16 + 3 * M1;       // 1M
  unsigned short* kh    = ws16 + 4 * M1;       // 8M (later reused as vT)
  unsigned short* k16   = ws16 + 12 * M1;      // 8M
  unsigned short* v16   = ws16 + 20 * M1;      // 8M (later reused as ctx)
  unsigned short* q16   = ws16 + 28 * M1;      // 8M  -> 36M u16 = 72 MB
  unsigned short* vT    = kh;                  // after KV GEMM, kh is dead
  unsigned short* ctx   = v16;                 // after k_vt, v16 is dead

  float* outF   = (float*)d_out;               // out: 8388608 f32
  float* probsF = outF + M8;                   // probs: 134217728 f32

  k_build_w<<<dim3(16384), dim3(256), 0, stream>>>(
      wq, wkv, wo, r_q, s_q, r_kv, s_kv, r_o, s_o,
      rm_q, sm_q, rm_kv, sm_kv, rm_o, sm_o, src_i, tgt_i,
      Wq16, Wkv16, Wo16);

  k_cvt<<<dim3(4096), dim3(256), 0, stream>>>(key, kh);

  // kv = key @ Wkv^T -> k16 (cols 0..1023), v16 (cols 1024..2047)
  k_gemm<1, 1><<<dim3(16, 64), dim3(256), 0, stream>>>(nullptr, kh, Wkv16, k16, v16, nullptr);
  // per-head V transpose -> vT (overwrites kh)
  k_vt<<<dim3(2048), dim3(256), 0, stream>>>(v16, vT);
  // q = query @ Wq^T (scaling folded), f32 A staged in-kernel
  k_gemm<0, 0><<<dim3(8, 64), dim3(256), 0, stream>>>(query, nullptr, Wq16, q16, nullptr, nullptr);

  k_attn<<<dim3(4096), dim3(256), 0, stream>>>(q16, k16, vT, probsF, ctx);

  // out = ctx @ Wo^T -> f32 d_out
  k_gemm<1, 2><<<dim3(8, 64), dim3(256), 0, stream>>>(nullptr, ctx, Wo16, nullptr, nullptr, outF);
}

// Round 8
// 393.042 us; speedup vs baseline: 1.2196x; 1.2196x over previous
//
#include <hip/hip_runtime.h>
#include <hip/hip_bf16.h>

// MFW encdec multihead attention, MI355X — all-fp16, v4 attn (v2 skeleton +
// swapped QK^T + b64 P-writes + barrier-free PV from global vT).
// build W -> cvt q/k -> KV GEMM (split k16/v16) -> k_vt (V^T) -> Q GEMM ->
// attn -> out GEMM.  d_out FLOAT32: [out 8.4M | probs 134.2M].

typedef float  fx4 __attribute__((ext_vector_type(4)));
typedef short  sx8 __attribute__((ext_vector_type(8)));
typedef _Float16 hx8 __attribute__((ext_vector_type(8)));

__device__ __forceinline__ unsigned short f2h(float f) {
  return __builtin_bit_cast(unsigned short, (_Float16)f);
}
__device__ __forceinline__ float h2f(unsigned short h) {
  return (float)__builtin_bit_cast(_Float16, h);
}
__device__ __forceinline__ unsigned pk2h(float a, float b) {
  return __builtin_bit_cast(unsigned, __builtin_amdgcn_cvt_pkrtz(a, b));
}

__device__ __forceinline__ void gload_lds16(const void* g, void* l) {
  __builtin_amdgcn_global_load_lds((const __attribute__((address_space(1))) void*)g,
                                   (__attribute__((address_space(3))) void*)l, 16, 0, 0);
}

__device__ __forceinline__ fx4 mfma_h(sx8 a, sx8 b, fx4 c) {
  return __builtin_amdgcn_mfma_f32_16x16x32_f16(__builtin_bit_cast(hx8, a),
                                                __builtin_bit_cast(hx8, b), c, 0, 0, 0);
}

// LDS-only barrier (global stores stay in flight)
__device__ __forceinline__ void bar_lgkm() {
  __builtin_amdgcn_sched_barrier(0);
  asm volatile("s_waitcnt lgkmcnt(0)" ::: "memory");
  __builtin_amdgcn_s_barrier();
  __builtin_amdgcn_sched_barrier(0);
}

// ---------------------------------------------------------------------------
// Kernel 1: build adapted weights (fp16).
// ---------------------------------------------------------------------------
__global__ void k_build_w(
    const float* wq, const float* wkv, const float* wo,
    const float* r_q, const float* s_q, const float* r_kv, const float* s_kv,
    const float* r_o, const float* s_o,
    const float* rm_q, const float* sm_q, const float* rm_kv, const float* sm_kv,
    const float* rm_o, const float* sm_o,
    const int* src_i, const int* tgt_i,
    unsigned short* Wq16, unsigned short* Wkv16, unsigned short* Wo16)
{
  const int it = tgt_i[0], is = src_i[0];
  const int gid = blockIdx.x * 256 + threadIdx.x;
  const int mat = gid >> 20;
  const int idx = gid & 1048575;
  const int o = idx >> 10, i = idx & 1023;
  float lrm = 0.f, lr = 0.f;
  if (mat == 0) {
    #pragma unroll
    for (int r = 0; r < 4; ++r) {
      lrm += rm_q[(it * 4 + r) * 1024 + o] * sm_q[(is * 4 + r) * 1024 + i];
      lr  += r_q [(it * 4 + r) * 1024 + o] * s_q [(is * 4 + r) * 1024 + i];
    }
    Wq16[idx] = f2h((wq[idx] * lrm + lr) * 0.125f);
  } else if (mat == 1) {
    #pragma unroll
    for (int r = 0; r < 4; ++r) {
      lrm += rm_kv[(it * 4 + r) * 2048 + o] * sm_kv[(is * 4 + r) * 1024 + i];
      lr  += r_kv [(it * 4 + r) * 2048 + o] * s_kv [(is * 4 + r) * 1024 + i];
    }
    Wkv16[idx] = f2h(wkv[idx] * lrm + lr);
  } else if (mat == 2) {
    #pragma unroll
    for (int r = 0; r < 4; ++r) {
      lrm += rm_kv[(it * 4 + r) * 2048 + 1024 + o] * sm_kv[(is * 4 + r) * 1024 + i];
      lr  += r_kv [(it * 4 + r) * 2048 + 1024 + o] * s_kv [(is * 4 + r) * 1024 + i];
    }
    Wkv16[1048576 + idx] = f2h(wkv[1048576 + idx] * lrm + lr);
  } else {
    #pragma unroll
    for (int r = 0; r < 4; ++r) {
      lrm += rm_o[(it * 4 + r) * 1024 + o] * sm_o[(is * 4 + r) * 1024 + i];
      lr  += r_o [(it * 4 + r) * 1024 + o] * s_o [(is * 4 + r) * 1024 + i];
    }
    Wo16[idx] = f2h(wo[idx] * lrm + lr);
  }
}

// ---------------------------------------------------------------------------
// Kernel 1b: convert query/key f32 -> fp16 (8 elems/thread).
// ---------------------------------------------------------------------------
__global__ void k_cvt(const float* q, const float* k,
                      unsigned short* qh, unsigned short* kh)
{
  const int gid = blockIdx.x * 256 + threadIdx.x;   // 0 .. 2M-1
  const bool isq = gid < 1048576;
  const size_t off = (size_t)(isq ? gid : gid - 1048576) * 8;
  const float* s = (isq ? q : k) + off;
  unsigned short* d = (isq ? qh : kh) + off;
  fx4 a = *(const fx4*)s, bv = *(const fx4*)(s + 4);
  sx8 h;
  #pragma unroll
  for (int j = 0; j < 4; ++j) { h[j] = (short)f2h(a[j]); h[4 + j] = (short)f2h(bv[j]); }
  *(sx8*)d = h;
}

// ---------------------------------------------------------------------------
// Kernel 2: C = A * B^T, A fp16 [8192][1024], B fp16 [N][1024].
// 128x128 tile, BK=32, 4 waves, m97 structure.
// OUT 0: fp16 C[row*1024+col]   OUT 1: split C0/C1 at col 1024   OUT 2: f32.
// ---------------------------------------------------------------------------
template<int OUT>
__global__ __launch_bounds__(256, 2) void k_gemm(
    const unsigned short* A, const unsigned short* B,
    unsigned short* C0, unsigned short* C1, float* Cf)
{
  __shared__ unsigned short lds[2][2][4096];
  const int tid = threadIdx.x;
  const int l = tid & 63, wid = tid >> 6;
  const int wr = wid >> 1, wc = wid & 1;
  const int mBase = blockIdx.y * 128, nBase = blockIdx.x * 128;
  const int brow = tid >> 2, bc8 = (tid & 3) * 8;

  fx4 acc[4][4] = {};

  auto stage = [&](int buf, int kt) {
    const int kB = kt * 32;
    gload_lds16(B + (size_t)(nBase + brow) * 1024 + kB + bc8,      &lds[buf][1][tid * 8]);
    gload_lds16(B + (size_t)(nBase + 64 + brow) * 1024 + kB + bc8, &lds[buf][1][2048 + tid * 8]);
    gload_lds16(A + (size_t)(mBase + brow) * 1024 + kB + bc8,      &lds[buf][0][tid * 8]);
    gload_lds16(A + (size_t)(mBase + 64 + brow) * 1024 + kB + bc8, &lds[buf][0][2048 + tid * 8]);
  };

  auto compute = [&](int buf) {
    sx8 af[4], bfv[4];
    #pragma unroll
    for (int x = 0; x < 4; ++x) {
      af[x]  = *(const sx8*)&lds[buf][0][(wr * 64 + x * 16 + (l & 15)) * 32 + (l >> 4) * 8];
      bfv[x] = *(const sx8*)&lds[buf][1][(wc * 64 + x * 16 + (l & 15)) * 32 + (l >> 4) * 8];
    }
    #pragma unroll
    for (int mi = 0; mi < 4; ++mi)
      #pragma unroll
      for (int ni = 0; ni < 4; ++ni)
        acc[mi][ni] = mfma_h(af[mi], bfv[ni], acc[mi][ni]);
  };

  stage(0, 0);
  __syncthreads();
  for (int kt = 0; kt < 32; ++kt) {
    const int buf = kt & 1;
    if (kt + 1 < 32) stage(buf ^ 1, kt + 1);
    compute(buf);
    __syncthreads();
  }

  #pragma unroll
  for (int mi = 0; mi < 4; ++mi)
    #pragma unroll
    for (int ni = 0; ni < 4; ++ni)
      #pragma unroll
      for (int i = 0; i < 4; ++i) {
        const size_t row = (size_t)(mBase + wr * 64 + mi * 16 + (l >> 4) * 4 + i);
        const int col = nBase + wc * 64 + ni * 16 + (l & 15);
        const float x = acc[mi][ni][i];
        if constexpr (OUT == 0)      C0[row * 1024 + col] = f2h(x);
        else if constexpr (OUT == 2) Cf[row * 1024 + col] = x;
        else {
          if (nBase < 1024) C0[row * 1024 + col] = f2h(x);
          else              C1[row * 1024 + (col - 1024)] = f2h(x);
        }
      }
}

// ---------------------------------------------------------------------------
// Kernel 2b: per-head V transpose (validated round 6):
// v16[(k*8+b)*1024 + h*64 + d] -> vT[((b*16+h)*64 + d)*1024 + k].
// ---------------------------------------------------------------------------
__global__ __launch_bounds__(256) void k_vt(const unsigned short* v16, unsigned short* vT)
{
  __shared__ unsigned short t[64 * 72];
  const int tid = threadIdx.x;
  const int head = blockIdx.x >> 4, kb = blockIdx.x & 15;
  const int b = head >> 4, hh = head & 15;
  const int kl = tid >> 2, part = tid & 3;
  #pragma unroll
  for (int u = 0; u < 2; ++u) {
    sx8 v = *(const sx8*)&v16[(size_t)((kb * 64 + kl) * 8 + b) * 1024 + hh * 64 + part * 16 + u * 8];
    *(sx8*)&t[kl * 72 + part * 16 + u * 8] = v;
  }
  __syncthreads();
  const int dr = tid >> 2;
  unsigned short out[16];
  #pragma unroll
  for (int j = 0; j < 16; ++j) out[j] = t[(part * 16 + j) * 72 + dr];
  unsigned short* dst = vT + (size_t)((b * 16 + hh) * 64 + dr) * 1024 + kb * 64 + part * 16;
  *(sx8*)dst       = *(sx8*)&out[0];
  *(sx8*)(dst + 8) = *(sx8*)&out[8];
}

// ---------------------------------------------------------------------------
// Kernel 3: FUSED attn v4.  Block = (head, 64 q), 512 thr, 8 waves (qg, half).
// P0: K-slice (128 KB) preload -> Pl (16B-chunk XOR swizzle).
// P1: SWAPPED QK^T: acc[s] = mfma(Kfrag, Qfrag) -> lane owns one q-row,
//     k lane-local.  P2: softmax (2 shfl + cross-half LDS).
// P3a: P fp16 -> Pl via cvt_pkrtz + ds_write_b64 (k-contiguous).
// P4: PV, NO barriers: pa from Pl (b128), V B-frags b128 straight from
//     global vT (L2-resident, XCD swizzle).  ctx out.
// P5: coalesced probs f32 stores (drain into block boundary).
// ---------------------------------------------------------------------------
__global__ __launch_bounds__(512, 2) void k_attn(
    const unsigned short* q16, const unsigned short* k16, const unsigned short* vT,
    float* probsF, unsigned short* ctx)
{
  __shared__ __align__(16) unsigned short Pl[65536];   // K-slice, then P (swizzled)
  __shared__ float redm[128], reds[128];               // [q][half]

  const int tid = threadIdx.x, l = tid & 63, wid = tid >> 6;
  const int qg = wid >> 1, half = wid & 1;   // P4 reuses half as dh
  const int bid = blockIdx.x;
  const int logical = (bid & 7) * 256 + (bid >> 3);    // XCD-grouped, bijective
  const int head = logical >> 4, qb = logical & 15;
  const int b = head >> 4, hh = head & 15;

  // ---- P0: K preload (pre-swizzled source, linear LDS dest) ----------------
  #pragma unroll
  for (int r = 0; r < 16; ++r) {
    const int e = r * 512 + tid;
    const int lk = e >> 3, ch = e & 7;
    gload_lds16(k16 + (size_t)(lk * 8 + b) * 1024 + hh * 64 + ((ch ^ (lk & 7)) * 8),
                &Pl[e * 8]);
  }
  sx8 qf[2];
  {
    const int qrow = qb * 64 + qg * 16 + (l & 15);
    const size_t qoff = (size_t)(qrow * 8 + b) * 1024 + hh * 64 + (l >> 4) * 8;
    qf[0] = *(const sx8*)&q16[qoff];
    qf[1] = *(const sx8*)&q16[qoff + 32];
  }
  __syncthreads();

  // ---- P1: swapped QK^T, zero barriers --------------------------------------
  // acc[s][i] = scores[k = half*512 + s*16 + (l>>4)*4 + i][q = qg*16 + (l&15)]
  fx4 acc[32];
  #pragma unroll
  for (int s = 0; s < 32; ++s) acc[s] = fx4{0.f, 0.f, 0.f, 0.f};

  #pragma unroll
  for (int s = 0; s < 32; ++s) {
    const int lk = half * 512 + s * 16 + (l & 15);
    sx8 kb0 = *(const sx8*)&Pl[lk * 64 + (((l >> 4)) ^ (l & 7)) * 8];
    sx8 kb1 = *(const sx8*)&Pl[lk * 64 + ((4 + (l >> 4)) ^ (l & 7)) * 8];
    acc[s] = mfma_h(kb0, qf[0], acc[s]);   // A = K-tile, B = Q-tile
    acc[s] = mfma_h(kb1, qf[1], acc[s]);
  }

  // ---- P2: softmax (lane owns q = qg*16 + (l&15)) ---------------------------
  const int q = qg * 16 + (l & 15);
  float m = -3e38f;
  #pragma unroll
  for (int s = 0; s < 32; ++s)
    #pragma unroll
    for (int i = 0; i < 4; ++i) m = fmaxf(m, acc[s][i]);
  m = fmaxf(m, __shfl_xor(m, 16));
  m = fmaxf(m, __shfl_xor(m, 32));
  if ((l >> 4) == 0) redm[q * 2 + half] = m;
  bar_lgkm();                                          // also: all K reads done
  const float mf = fmaxf(redm[q * 2], redm[q * 2 + 1]);
  float ssum = 0.f;
  #pragma unroll
  for (int s = 0; s < 32; ++s)
    #pragma unroll
    for (int i = 0; i < 4; ++i) {
      const float e = __expf(acc[s][i] - mf);
      acc[s][i] = e;
      ssum += e;
    }
  ssum += __shfl_xor(ssum, 16);
  ssum += __shfl_xor(ssum, 32);
  if ((l >> 4) == 0) reds[q * 2 + half] = ssum;
  bar_lgkm();
  const float inv = 1.0f / (reds[q * 2] + reds[q * 2 + 1]);

  // ---- P3a: P fp16 -> Pl, k-contiguous b64 writes ---------------------------
  #pragma unroll
  for (int s = 0; s < 32; ++s) {
    const int k0 = half * 512 + s * 16 + (l >> 4) * 4;
    uint2 w;
    w.x = pk2h(acc[s][0] * inv, acc[s][1] * inv);
    w.y = pk2h(acc[s][2] * inv, acc[s][3] * inv);
    *(uint2*)&Pl[q * 1024 + (((k0 >> 3) ^ (q & 7)) << 3) + (k0 & 7)] = w;
  }
  bar_lgkm();                                          // P complete

  // ---- P4: PV, barrier-free (V B-frags from global vT) ----------------------
  const int dh = half;
  fx4 cacc[2] = {};
  const unsigned short* vrow = vT + (size_t)((b * 16 + hh) * 64 + dh * 32 + (l & 15)) * 1024;
  #pragma unroll
  for (int c = 0; c < 32; ++c) {
    const int k0 = c * 32 + (l >> 4) * 8;
    sx8 pa  = *(const sx8*)&Pl[q * 1024 + (((k0 >> 3) ^ (q & 7)) << 3)];
    sx8 vb0 = *(const sx8*)&vrow[k0];
    sx8 vb1 = *(const sx8*)&vrow[16 * 1024 + k0];
    cacc[0] = mfma_h(pa, vb0, cacc[0]);
    cacc[1] = mfma_h(pa, vb1, cacc[1]);
  }

  // ctx out (fp16, (lq,b,E) layout)
  #pragma unroll
  for (int ni = 0; ni < 2; ++ni)
    #pragma unroll
    for (int i = 0; i < 4; ++i) {
      const int qrow = qb * 64 + qg * 16 + (l >> 4) * 4 + i;
      const int d = dh * 32 + ni * 16 + (l & 15);
      ctx[(size_t)(qrow * 8 + b) * 1024 + hh * 64 + d] = f2h(cacc[ni][i]);
    }

  // ---- P5: coalesced probs f32 stores from Pl -------------------------------
  {
    const size_t pbase = (size_t)head * 1048576;
    #pragma unroll
    for (int i = 0; i < 32; ++i) {
      const int row = wid * 8 + (i >> 2);
      const int col = (i & 3) * 256 + l * 4;
      const int c16 = ((col >> 3) ^ (row & 7));
      const unsigned* raw = (const unsigned*)&Pl[row * 1024 + c16 * 8 + (col & 7)];
      const unsigned r0 = raw[0], r1 = raw[1];
      fx4 o;
      o[0] = h2f((unsigned short)(r0 & 0xffffu)); o[1] = h2f((unsigned short)(r0 >> 16));
      o[2] = h2f((unsigned short)(r1 & 0xffffu)); o[3] = h2f((unsigned short)(r1 >> 16));
      *(fx4*)&probsF[pbase + (size_t)(qb * 64 + row) * 1024 + col] = o;
    }
  }
}

// ---------------------------------------------------------------------------
extern "C" void kernel_launch(void* const* d_in, const int* in_sizes, int n_in,
                              void* d_out, int out_size, void* d_ws, size_t ws_size,
                              hipStream_t stream)
{
  const float* query = (const float*)d_in[0];
  const float* key   = (const float*)d_in[1];
  const float* wq    = (const float*)d_in[2];
  const float* wkv   = (const float*)d_in[3];
  const float* wo    = (const float*)d_in[4];
  const float* r_q   = (const float*)d_in[5];
  const float* s_q   = (const float*)d_in[6];
  const float* r_kv  = (const float*)d_in[7];
  const float* s_kv  = (const float*)d_in[8];
  const float* r_o   = (const float*)d_in[9];
  const float* s_o   = (const float*)d_in[10];
  const float* rm_q  = (const float*)d_in[11];
  const float* sm_q  = (const float*)d_in[12];
  const float* rm_kv = (const float*)d_in[13];
  const float* sm_kv = (const float*)d_in[14];
  const float* rm_o  = (const float*)d_in[15];
  const float* sm_o  = (const float*)d_in[16];
  const int* src_i   = (const int*)d_in[17];
  const int* tgt_i   = (const int*)d_in[18];

  unsigned short* ws16 = (unsigned short*)d_ws;
  const size_t M1 = 1048576, M8 = 8388608;
  unsigned short* Wq16  = ws16;                // 1M
  unsigned short* Wkv16 = ws16 + M1;           // 2M
  unsigned short* Wo16  = ws16 + 3 * M1;       // 1M
  unsigned short* qh    = ws16 + 4 * M1;       // 8M (-> ctx after Q GEMM+attn)
  unsigned short* kh    = ws16 + 12 * M1;      // 8M (-> vT after KV GEMM)
  unsigned short* k16   = ws16 + 20 * M1;      // 8M
  unsigned short* v16   = ws16 + 28 * M1;      // 8M (-> q16 after k_vt)
                                               // total 36M u16 = 72 MB
  unsigned short* vT  = kh;                    // kh dead after KV GEMM
  unsigned short* q16 = v16;                   // v16 dead after k_vt
  unsigned short* ctx = qh;                    // qh dead after Q GEMM

  float* outF   = (float*)d_out;               // out: 8388608 f32
  float* probsF = outF + M8;                   // probs: 134217728 f32

  k_build_w<<<dim3(16384), dim3(256), 0, stream>>>(
      wq, wkv, wo, r_q, s_q, r_kv, s_kv, r_o, s_o,
      rm_q, sm_q, rm_kv, sm_kv, rm_o, sm_o, src_i, tgt_i,
      Wq16, Wkv16, Wo16);

  k_cvt<<<dim3(8192), dim3(256), 0, stream>>>(query, key, qh, kh);

  // kv = key @ Wkv^T -> k16 (cols 0..1023) / v16 (cols 1024..2047)
  k_gemm<1><<<dim3(16, 64), dim3(256), 0, stream>>>(kh, Wkv16, k16, v16, nullptr);
  // per-head V transpose -> vT (overwrites kh)
  k_vt<<<dim3(2048), dim3(256), 0, stream>>>(v16, vT);
  // q = query @ Wq^T (scaling folded) -> q16 (overwrites v16)
  k_gemm<0><<<dim3(8, 64), dim3(256), 0, stream>>>(qh, Wq16, q16, nullptr, nullptr);

  k_attn<<<dim3(2048), dim3(512), 0, stream>>>(q16, k16, vT, probsF, ctx);

  // out = ctx @ Wo^T -> f32 d_out
  k_gemm<2><<<dim3(8, 64), dim3(256), 0, stream>>>(ctx, Wo16, nullptr, nullptr, outF);
}